// Round 4
// baseline (1161.663 us; speedup 1.0000x reference)
//
#include <hip/hip_runtime.h>

// ---------------- problem constants ----------------
#define N_NODES 100000
#define N_EDGES 1600000
#define DN 128
#define DE 48
#define HDIM 256
#define KX 192             // layer-1 self width padded: 176 real cols + 16 zeros (chunk-align)
#define NPAD 100096        // 782 * 128 (GEMM row padding; also 391*256 scan width)
#define NB 391             // scan blocks = NPAD/256

typedef __bf16 bf16;
typedef __bf16 bf16x2 __attribute__((ext_vector_type(2)));
typedef __bf16 bf16x8 __attribute__((ext_vector_type(8)));
typedef float  f32x4  __attribute__((ext_vector_type(4)));

// ---------------- workspace layout (bytes) ----------------
#define O_DEG  0UL                      // NPAD int
#define O_ROW  400384UL                 // NPAD int (rowptr)
#define O_CUR  800768UL                 // NPAD int (fill cursor)
#define O_PRE  1201152UL                // NPAD int (block-local prefix)
#define O_PART 1601536UL                // 512 int (block partials)
#define O_CSR  1603584UL                // E int2 (src, eid) = 12.8 MB
#define O_X    14403584UL               // NPAD x 192 bf16 = 38.4 MB (layer-1 self feats)
#define O_H2A  52840448UL               // NPAD x 256 bf16 = 51.2 MB (layer-1 output)
#define O_W1   104089600UL              // 256 x 384 bf16 (padded)
#define O_W2   104286208UL              // 256 x 512 bf16; end ~104.5 MB

__device__ __forceinline__ float bf_lo(unsigned u) { return __uint_as_float(u << 16); }
__device__ __forceinline__ float bf_hi(unsigned u) { return __uint_as_float(u & 0xffff0000u); }
__device__ __forceinline__ unsigned bf_pk(float a, float b) {
    union { bf16x2 v; unsigned u; } t;
    t.v.x = (bf16)a; t.v.y = (bf16)b;
    return t.u;
}

// ---------------- weight prep: bf16, transposed to [n][k], self/neigh stacked in k ----------------
// Wt1: [256][384], k<176 = Ws1, 176..191 = 0, 192..367 = Wn1, 368..383 = 0
// Wt2: [256][512], k<256 = Ws2, else Wn2
__global__ void k_prep_weights(const float* __restrict__ Ws1, const float* __restrict__ Wn1,
                               const float* __restrict__ Ws2, const float* __restrict__ Wn2,
                               bf16* __restrict__ Wt1, bf16* __restrict__ Wt2) {
    int tid = blockIdx.x * 256 + threadIdx.x;
    if (tid < HDIM * 384) {
        int n = tid / 384, k = tid - n * 384;
        float v = 0.0f;
        if (k < 176) v = Ws1[k * HDIM + n];
        else if (k >= 192 && k < 368) v = Wn1[(k - 192) * HDIM + n];
        Wt1[n * 384 + k] = (bf16)v;
    } else {
        int t2 = tid - HDIM * 384;
        int n = t2 / 512, k = t2 - n * 512;
        float v = (k < HDIM) ? Ws2[k * HDIM + n] : Wn2[(k - HDIM) * HDIM + n];
        Wt2[n * 512 + k] = (bf16)v;
    }
}

// ---------------- CSR build ----------------
__global__ void k_count(const int* __restrict__ dst, int* __restrict__ deg) {
    int e = blockIdx.x * 256 + threadIdx.x;
    if (e < N_EDGES) atomicAdd(&deg[dst[e]], 1);
}

template <int NT>
__device__ __forceinline__ int block_scan_inc(int v, int* lds) {
    int tid = threadIdx.x;
    lds[tid] = v;
#pragma unroll
    for (int off = 1; off < NT; off <<= 1) {
        __syncthreads();
        int t = (tid >= off) ? lds[tid - off] : 0;
        __syncthreads();
        lds[tid] += t;
    }
    return lds[tid];
}

__global__ void k_scanA(const int* __restrict__ deg, int* __restrict__ presum,
                        int* __restrict__ part) {
    __shared__ int lds[256];
    int idx = blockIdx.x * 256 + threadIdx.x;
    int v = (idx < N_NODES) ? deg[idx] : 0;
    int inc = block_scan_inc<256>(v, lds);
    presum[idx] = inc - v;
    if (threadIdx.x == 255) part[blockIdx.x] = inc;
}

__global__ void k_scanB(int* __restrict__ part) {
    __shared__ int lds[512];
    int t = threadIdx.x;
    int v = (t < NB) ? part[t] : 0;
    int inc = block_scan_inc<512>(v, lds);
    if (t < NB) part[t] = inc - v;   // exclusive
}

__global__ void k_scanC(const int* __restrict__ presum, const int* __restrict__ part,
                        int* __restrict__ rowptr, int* __restrict__ cursor) {
    int idx = blockIdx.x * 256 + threadIdx.x;   // covers all NPAD (pad rowptr valid, deg=0)
    int v = presum[idx] + part[blockIdx.x];
    rowptr[idx] = v; cursor[idx] = v;
}

__global__ void k_fill(const int* __restrict__ src, const int* __restrict__ dst,
                       int* __restrict__ cursor, int2* __restrict__ csr) {
    int e = blockIdx.x * 256 + threadIdx.x;   // exact grid
    int p = atomicAdd(&cursor[dst[e]], 1);
    csr[p] = make_int2(src[e], e);
}

// ---------------- layer-1 input build: x[n] = [bf16(fn[n]) | mean_e fe | 0-pad] ----------------
__global__ void k_agg_edges(const float* __restrict__ fn, const float* __restrict__ fe,
                            const int* __restrict__ rowptr, const int* __restrict__ deg,
                            const int2* __restrict__ csr, bf16* __restrict__ x) {
    int node = blockIdx.x * 4 + (threadIdx.x >> 6);  // grid 25000 exact
    int lane = threadIdx.x & 63;
    bf16* row = x + (size_t)node * KX;
    float2 f = *(const float2*)(fn + (size_t)node * DN + lane * 2);
    *(unsigned*)&row[lane * 2] = bf_pk(f.x, f.y);
    int base = rowptr[node], d = deg[node];
    int slot = lane / 12;           // 0..3 active, 4-5 idle
    int sub  = lane - slot * 12;    // float4 index within the 192 B fe row
    bool act = lane < 48;
    f32x4 s = {0.f, 0.f, 0.f, 0.f};
    for (int c = 0; c < d; c += 64) {
        int nn = min(d - c, 64);
        int myE = (lane < nn) ? csr[base + c + lane].y : 0;
        for (int i = 0; i < nn; i += 16) {
            f32x4 v[4];
#pragma unroll
            for (int g = 0; g < 4; ++g) {
                int ei = i + g * 4 + slot;
                int e = __shfl(myE, ei);
                v[g] = (f32x4){0.f, 0.f, 0.f, 0.f};
                if (act && ei < nn)
                    v[g] = *(const f32x4*)(fe + (size_t)e * DE + sub * 4);
            }
            s += (v[0] + v[1]) + (v[2] + v[3]);
        }
    }
#pragma unroll
    for (int k = 0; k < 4; ++k) {
        float t = s[k];
        t += __shfl(s[k], lane + 12);
        t += __shfl(s[k], lane + 24);
        t += __shfl(s[k], lane + 36);
        s[k] = t;
    }
    if (lane < 12) {
        float r = 1.0f / (float)max(d, 1);
        uint2 o;
        o.x = bf_pk(s[0] * r, s[1] * r);
        o.y = bf_pk(s[2] * r, s[3] * r);
        *((uint2*)(row + DN) + lane) = o;
    } else if (lane < 16) {
        *((uint2*)(row + DN) + lane) = make_uint2(0u, 0u);   // zero-pad cols 176..191
    }
}

// ---------------- fused aggregate + GEMM ----------------
// Per block: 128 rows x 256 cols of  out = [X | mean_dst X[src]] @ Wt^T + bias.
// Phase 1: 4 waves x 32 nodes gather+mean X[src] rows into LDS (swizzled pages).
// Phase 2: K-loop; A-self + B from global (L1/L2-hot), A-neigh from LDS.
// KST = self K-chunks (K = 2*KST*32); KS = X row stride (elems); LPE = lanes/row (KS/8).
template <int KST, int KS, int LPE, bool RELU, typename OT>
__global__ __launch_bounds__(256, 2) void k_fused(const bf16* __restrict__ X,
                                                  const bf16* __restrict__ Wt,
                                                  const float* __restrict__ bias,
                                                  const int* __restrict__ rowptr,
                                                  const int* __restrict__ deg,
                                                  const int2* __restrict__ csr,
                                                  OT* __restrict__ out) {
    constexpr int K = 2 * KST * 32;
    // KST pages of [128 rows][32 bf16], 16B units XOR-swizzled by (row&3): conflict-free b128
    __shared__ __align__(16) bf16 nb[KST * 128 * 32];

    const int tid = threadIdx.x;
    const int lane = tid & 63, wq = tid >> 6;
    const int rowBase = blockIdx.x * 128;

    // ---- phase 1: neighbor-mean gather into LDS ----
    {
        int slot, sub; bool act;
        if (LPE == 32) { slot = lane >> 5; sub = lane & 31; act = true; }
        else { slot = (lane < LPE) ? 0 : ((lane < 2 * LPE) ? 1 : 2); sub = lane - slot * LPE; act = (slot < 2); }
        for (int nl = 0; nl < 32; ++nl) {
            int node = rowBase + wq * 32 + nl;
            int base = rowptr[node], d = deg[node];
            float s[8] = {0.f, 0.f, 0.f, 0.f, 0.f, 0.f, 0.f, 0.f};
            for (int c = 0; c < d; c += 64) {
                int nn = min(d - c, 64);
                int mySv = (lane < nn) ? csr[base + c + lane].x : 0;
                for (int i = 0; i < nn; i += 16) {
                    uint4 q[8];
#pragma unroll
                    for (int g = 0; g < 8; ++g) {
                        int ei = i + g * 2 + slot;
                        int sv = __shfl(mySv, ei);
                        q[g] = make_uint4(0u, 0u, 0u, 0u);
                        if (act && ei < nn)
                            q[g] = *((const uint4*)(X + (size_t)sv * KS) + sub);
                    }
#pragma unroll
                    for (int g = 0; g < 8; ++g) {
                        s[0] += bf_lo(q[g].x); s[1] += bf_hi(q[g].x);
                        s[2] += bf_lo(q[g].y); s[3] += bf_hi(q[g].y);
                        s[4] += bf_lo(q[g].z); s[5] += bf_hi(q[g].z);
                        s[6] += bf_lo(q[g].w); s[7] += bf_hi(q[g].w);
                    }
                }
            }
#pragma unroll
            for (int k = 0; k < 8; ++k) s[k] += __shfl(s[k], lane + LPE);
            if (lane < LPE) {
                float r = 1.0f / (float)max(d, 1);
                uint4 o;
                o.x = bf_pk(s[0] * r, s[1] * r);
                o.y = bf_pk(s[2] * r, s[3] * r);
                o.z = bf_pk(s[4] * r, s[5] * r);
                o.w = bf_pk(s[6] * r, s[7] * r);
                int row = wq * 32 + nl;
                int kc = sub >> 2, lqw = sub & 3;
                *(uint4*)&nb[kc * 4096 + row * 32 + 8 * (lqw ^ (row & 3))] = o;
            }
        }
    }
    __syncthreads();

    // ---- phase 2: MFMA K-loop ----
    const int wr = (wq & 1) * 64, wc = (wq >> 1) * 128;
    const int lm = lane & 15, lq = lane >> 4;
    f32x4 acc[4][8] = {};

    for (int kt = 0; kt < KST; ++kt) {               // self half: A from global X
        bf16x8 af[4];
#pragma unroll
        for (int mi = 0; mi < 4; ++mi)
            af[mi] = *(const bf16x8*)&X[(size_t)(rowBase + wr + mi * 16 + lm) * KS + kt * 32 + lq * 8];
#pragma unroll
        for (int ni = 0; ni < 8; ++ni) {
            bf16x8 bv = *(const bf16x8*)&Wt[(size_t)(wc + ni * 16 + lm) * K + kt * 32 + lq * 8];
#pragma unroll
            for (int mi = 0; mi < 4; ++mi)
                acc[mi][ni] = __builtin_amdgcn_mfma_f32_16x16x32_bf16(af[mi], bv, acc[mi][ni], 0, 0, 0);
        }
    }
    for (int kt = 0; kt < KST; ++kt) {               // neigh half: A from LDS
        bf16x8 af[4];
#pragma unroll
        for (int mi = 0; mi < 4; ++mi) {
            int row = wr + mi * 16 + lm;
            af[mi] = *(const bf16x8*)&nb[kt * 4096 + row * 32 + 8 * (lq ^ (row & 3))];
        }
#pragma unroll
        for (int ni = 0; ni < 8; ++ni) {
            bf16x8 bv = *(const bf16x8*)&Wt[(size_t)(wc + ni * 16 + lm) * K + (KST + kt) * 32 + lq * 8];
#pragma unroll
            for (int mi = 0; mi < 4; ++mi)
                acc[mi][ni] = __builtin_amdgcn_mfma_f32_16x16x32_bf16(af[mi], bv, acc[mi][ni], 0, 0, 0);
        }
    }

    // ---- epilogue ----
#pragma unroll
    for (int ni = 0; ni < 8; ++ni) {
        const int gcol = wc + ni * 16 + lm;
        const float bvv = bias[gcol];
#pragma unroll
        for (int mi = 0; mi < 4; ++mi) {
#pragma unroll
            for (int r2 = 0; r2 < 4; ++r2) {
                const int grow = rowBase + wr + mi * 16 + lq * 4 + r2;
                if (grow < N_NODES) {
                    float v = acc[mi][ni][r2] + bvv;
                    if (RELU) v = fmaxf(v, 0.0f);
                    out[(size_t)grow * HDIM + gcol] = (OT)v;
                }
            }
        }
    }
}

// ---------------- launcher ----------------
extern "C" void kernel_launch(void* const* d_in, const int* in_sizes, int n_in,
                              void* d_out, int out_size, void* d_ws, size_t ws_size,
                              hipStream_t stream) {
    const float* fn  = (const float*)d_in[0];
    const float* fe  = (const float*)d_in[1];
    const int*   src = (const int*)d_in[2];
    const int*   dst = (const int*)d_in[3];
    const float* Ws1 = (const float*)d_in[4];
    const float* Wn1 = (const float*)d_in[5];
    const float* b1  = (const float*)d_in[6];
    const float* Ws2 = (const float*)d_in[7];
    const float* Wn2 = (const float*)d_in[8];
    const float* b2  = (const float*)d_in[9];
    float* out = (float*)d_out;

    char* ws = (char*)d_ws;
    int*  deg    = (int*)(ws + O_DEG);
    int*  rowptr = (int*)(ws + O_ROW);
    int*  cursor = (int*)(ws + O_CUR);
    int*  presum = (int*)(ws + O_PRE);
    int*  part   = (int*)(ws + O_PART);
    int2* csr    = (int2*)(ws + O_CSR);
    bf16* x   = (bf16*)(ws + O_X);
    bf16* h2a = (bf16*)(ws + O_H2A);
    bf16* Wt1 = (bf16*)(ws + O_W1);
    bf16* Wt2 = (bf16*)(ws + O_W2);

    hipMemsetAsync(deg, 0, (size_t)NPAD * 4, stream);
    hipMemsetAsync((char*)x   + (size_t)N_NODES * KX * 2,   0, (size_t)(NPAD - N_NODES) * KX * 2, stream);
    hipMemsetAsync((char*)h2a + (size_t)N_NODES * HDIM * 2, 0, (size_t)(NPAD - N_NODES) * HDIM * 2, stream);

    k_prep_weights<<<(HDIM * 384 + HDIM * 512) / 256, 256, 0, stream>>>(Ws1, Wn1, Ws2, Wn2, Wt1, Wt2);

    // CSR build
    k_count<<<(N_EDGES + 255) / 256, 256, 0, stream>>>(dst, deg);
    k_scanA<<<NB, 256, 0, stream>>>(deg, presum, part);
    k_scanB<<<1, 512, 0, stream>>>(part);
    k_scanC<<<NB, 256, 0, stream>>>(presum, part, rowptr, cursor);
    k_fill<<<N_EDGES / 256, 256, 0, stream>>>(src, dst, cursor, csr);

    // layer-1 input
    k_agg_edges<<<N_NODES / 4, 256, 0, stream>>>(fn, fe, rowptr, deg, csr, x);

    // layer 1: fused neighbor-mean + GEMM + relu -> h2a (bf16)
    k_fused<6, KX, 24, true, bf16><<<NPAD / 128, 256, 0, stream>>>(x, Wt1, b1, rowptr, deg, csr, h2a);

    // layer 2: fused neighbor-mean + GEMM -> out (fp32)
    k_fused<8, HDIM, 32, false, float><<<NPAD / 128, 256, 0, stream>>>(h2a, Wt2, b2, rowptr, deg, csr, out);
}